// Round 9
// baseline (226.090 us; speedup 1.0000x reference)
//
#include <hip/hip_runtime.h>
#include <hip/hip_bf16.h>

#define NN 20000        // N_NODES
#define NE 640000       // N_EDGES
#define FEAT 416
#define EPB 16          // edges per block
#define EDGE_BLOCKS (NE / EPB)   // 40000

typedef float f32x4 __attribute__((ext_vector_type(4)));

// d_ws layout: int flag at byte 0 (1 = int32 layout, 2 = int64 layout),
// bb5 floats (NN*15) starting at byte 64.

__global__ __launch_bounds__(256) void prep_kernel(const float* __restrict__ bb,
                                                   const int* __restrict__ ei,
                                                   int* __restrict__ flag,
                                                   float* __restrict__ bb5) {
    int t = blockIdx.x * 256 + threadIdx.x;

    // dtype probe: if edge_index is int64, the high dword of each qword is 0
    // (values in [0, 20000)). With int32 data these are random indices,
    // P(all 64 == 0) ~ (1/20000)^64 ~ 0.
    if (blockIdx.x == 0 && threadIdx.x < 64) {
        int v = ei[2 * threadIdx.x + 1];
        unsigned long long m = __ballot(v != 0);
        if (threadIdx.x == 0) flag[0] = (m == 0ULL) ? 2 : 1;
    }

    if (t < NN) {
        const float* r = bb + (size_t)t * 12;
        float Nx = r[0], Ny = r[1], Nz = r[2];
        float CAx = r[3], CAy = r[4], CAz = r[5];
        float Cx = r[6], Cy = r[7], Cz = r[8];
        float Ox = r[9], Oy = r[10], Oz = r[11];
        float bx = CAx - Nx, by = CAy - Ny, bz = CAz - Nz;
        float cx = Cx - CAx, cy = Cy - CAy, cz = Cz - CAz;
        float ax = by * cz - bz * cy;
        float ay = bz * cx - bx * cz;
        float az = bx * cy - by * cx;
        float vx = -0.58273431f * ax + 0.56802827f * bx - 0.54067466f * cx + CAx;
        float vy = -0.58273431f * ay + 0.56802827f * by - 0.54067466f * cy + CAy;
        float vz = -0.58273431f * az + 0.56802827f * bz - 0.54067466f * cz + CAz;
        float* w = bb5 + (size_t)t * 15;
        w[0] = Nx;  w[1] = Ny;  w[2] = Nz;
        w[3] = CAx; w[4] = CAy; w[5] = CAz;
        w[6] = Cx;  w[7] = Cy;  w[8] = Cz;
        w[9] = Ox;  w[10] = Oy; w[11] = Oz;
        w[12] = vx; w[13] = vy; w[14] = vz;
    }
}

__device__ __forceinline__ void load_idx(const int* __restrict__ ei, int sel, int e,
                                         int& dst, int& src) {
    if (sel == 2) {            // int64 layout: low dword of qword
        dst = ei[2 * e];
        src = ei[2 * (NE + e)];
    } else {                   // int32 layout
        dst = ei[e];
        src = ei[NE + e];
    }
}

__global__ __launch_bounds__(256) void edge_kernel(const int* __restrict__ ei,
                                                   const float* __restrict__ bb5,
                                                   const int* __restrict__ flag,
                                                   float* __restrict__ out) {
    __shared__ float dist[EPB * 25];   // pre-scaled by 0.8 (= 1/sigma)
    __shared__ int sidx[EPB * 2];      // (dst, src) per edge

    const int tid = threadIdx.x;
    const int e0 = blockIdx.x * EPB;

    if (tid < EPB) {
        int dst, src;
        load_idx(ei, flag[0], e0 + tid, dst, src);
        sidx[tid * 2] = dst;
        sidx[tid * 2 + 1] = src;
    }
    __syncthreads();

    f32x4* out4 = reinterpret_cast<f32x4*>(out) + (size_t)e0 * 104;

    if (tid < 64) {
        // ---- Phase C (wave 0, concurrent with Phase A on waves 1-3)
        // freq[q] = 10^(-q/2), hardcoded (reference: exp(-q*ln(10000)/8)).
        // angle = (float)(dst-src) * freq; reduce in double to revolutions,
        // then raw v_sin/v_cos (hardware takes revolutions).
        int s = tid >> 2;
        int g = tid & 3;               // 0,1 = cos(f0-3, f4-7); 2,3 = sin
        int dst = sidx[s * 2], src = sidx[s * 2 + 1];
        float d = (float)(dst - src);
        bool hi = (g & 1);             // frequency block: f = hi*4 + k
        bool issin = (g >= 2);
        float fr[4];
        fr[0] = hi ? 0.01f                    : 1.0f;
        fr[1] = hi ? 0.0031622776601683794f   : 0.31622776601683794f;
        fr[2] = hi ? 0.001f                   : 0.1f;
        fr[3] = hi ? 0.00031622776601683794f  : 0.031622776601683794f;
        float v[4];
#pragma unroll
        for (int k = 0; k < 4; ++k) {
            float angle = d * fr[k];                        // f32, matches ref
            double t = (double)angle * 0.15915494309189535; // 1/(2*pi)
            double r = t - rint(t);                         // |r| <= 0.5 revolutions
            float rf = (float)r;
            float val;
            if (issin) {
                asm("v_sin_f32 %0, %1" : "=v"(val) : "v"(rf));
            } else {
                asm("v_cos_f32 %0, %1" : "=v"(val) : "v"(rf));
            }
            v[k] = val;
        }
        f32x4 r4;
        r4.x = v[0]; r4.y = v[1]; r4.z = v[2]; r4.w = v[3];
        out4[s * 104 + 100 + g] = r4;
    } else {
        // ---- Phase A (waves 1-3): 400 distances over 192 threads
        for (int item = tid - 64; item < EPB * 25; item += 192) {
            int s = item / 25;
            int p = item - s * 25;
            int i = p / 5;                 // src atom
            int j = p - i * 5;             // dst atom
            int dst = sidx[s * 2], src = sidx[s * 2 + 1];
            const float* S = bb5 + src * 15 + i * 3;
            const float* D = bb5 + dst * 15 + j * 3;
            float dx = S[0] - D[0] + 1e-8f;
            float dy = S[1] - D[1] + 1e-8f;
            float dz = S[2] - D[2] + 1e-8f;
            dist[item] = sqrtf(dx * dx + dy * dy + dz * dz) * 0.8f;
        }
    }
    __syncthreads();

    // ---- Phase B: RBF chunks, one float4 per thread, fully coalesced
    for (int item = tid; item < EPB * 100; item += 256) {
        int s = item / 100;
        int c = item - s * 100;        // chunk within edge's RBF region
        int p = c >> 2;                // pair index
        int g = c & 3;                 // 4-center group
        float a = dist[s * 25 + p];    // broadcast read (4 lanes share)
        int k0 = g * 4;
        f32x4 r;
        float u;
        u = a - (float)(k0 + 0) * (16.0f / 15.0f); r.x = __expf(-(u * u));
        u = a - (float)(k0 + 1) * (16.0f / 15.0f); r.y = __expf(-(u * u));
        u = a - (float)(k0 + 2) * (16.0f / 15.0f); r.z = __expf(-(u * u));
        u = a - (float)(k0 + 3) * (16.0f / 15.0f); r.w = __expf(-(u * u));
        out4[s * 104 + c] = r;
    }
}

extern "C" void kernel_launch(void* const* d_in, const int* in_sizes, int n_in,
                              void* d_out, int out_size, void* d_ws, size_t ws_size,
                              hipStream_t stream) {
    const float* bb = (const float*)d_in[0];
    const int* ei = (const int*)d_in[1];
    int* flag = (int*)d_ws;
    float* bb5 = (float*)((char*)d_ws + 64);
    float* out = (float*)d_out;

    hipLaunchKernelGGL(prep_kernel, dim3((NN + 255) / 256), dim3(256), 0, stream,
                       bb, ei, flag, bb5);
    hipLaunchKernelGGL(edge_kernel, dim3(EDGE_BLOCKS), dim3(256), 0, stream,
                       ei, bb5, flag, out);
}

// Round 10
// 200.667 us; speedup vs baseline: 1.1267x; 1.1267x over previous
//
#include <hip/hip_runtime.h>
#include <hip/hip_bf16.h>

#define NN 20000        // N_NODES
#define NE 640000       // N_EDGES
#define FEAT 416
#define EPB 16          // edges per block (EPB=64 regressed: VGPR pressure; wave-split regressed)
#define EDGE_BLOCKS (NE / EPB)   // 40000

typedef float f32x4 __attribute__((ext_vector_type(4)));

// d_ws layout: int flag at byte 0 (1 = int32 layout, 2 = int64 layout),
// bb5 floats (NN*15) starting at byte 64.

__global__ __launch_bounds__(256) void prep_kernel(const float* __restrict__ bb,
                                                   const int* __restrict__ ei,
                                                   int* __restrict__ flag,
                                                   float* __restrict__ bb5) {
    int t = blockIdx.x * 256 + threadIdx.x;

    // dtype probe: if edge_index is int64, the high dword of each qword is 0
    // (values in [0, 20000)). With int32 data these are random indices,
    // P(all 64 == 0) ~ (1/20000)^64 ~ 0.
    if (blockIdx.x == 0 && threadIdx.x < 64) {
        int v = ei[2 * threadIdx.x + 1];
        unsigned long long m = __ballot(v != 0);
        if (threadIdx.x == 0) flag[0] = (m == 0ULL) ? 2 : 1;
    }

    if (t < NN) {
        const float* r = bb + (size_t)t * 12;
        float Nx = r[0], Ny = r[1], Nz = r[2];
        float CAx = r[3], CAy = r[4], CAz = r[5];
        float Cx = r[6], Cy = r[7], Cz = r[8];
        float Ox = r[9], Oy = r[10], Oz = r[11];
        float bx = CAx - Nx, by = CAy - Ny, bz = CAz - Nz;
        float cx = Cx - CAx, cy = Cy - CAy, cz = Cz - CAz;
        float ax = by * cz - bz * cy;
        float ay = bz * cx - bx * cz;
        float az = bx * cy - by * cx;
        float vx = -0.58273431f * ax + 0.56802827f * bx - 0.54067466f * cx + CAx;
        float vy = -0.58273431f * ay + 0.56802827f * by - 0.54067466f * cy + CAy;
        float vz = -0.58273431f * az + 0.56802827f * bz - 0.54067466f * cz + CAz;
        float* w = bb5 + (size_t)t * 15;
        w[0] = Nx;  w[1] = Ny;  w[2] = Nz;
        w[3] = CAx; w[4] = CAy; w[5] = CAz;
        w[6] = Cx;  w[7] = Cy;  w[8] = Cz;
        w[9] = Ox;  w[10] = Oy; w[11] = Oz;
        w[12] = vx; w[13] = vy; w[14] = vz;
    }
}

__device__ __forceinline__ void load_idx(const int* __restrict__ ei, int sel, int e,
                                         int& dst, int& src) {
    if (sel == 2) {            // int64 layout: low dword of qword
        dst = ei[2 * e];
        src = ei[2 * (NE + e)];
    } else {                   // int32 layout
        dst = ei[e];
        src = ei[NE + e];
    }
}

__global__ __launch_bounds__(256) void edge_kernel(const int* __restrict__ ei,
                                                   const float* __restrict__ bb5,
                                                   const int* __restrict__ flag,
                                                   float* __restrict__ out) {
    __shared__ float dist[EPB * 25];   // pre-scaled by 0.8 (= 1/sigma)
    __shared__ int sidx[EPB * 2];      // (dst, src) per edge

    const int tid = threadIdx.x;
    const int e0 = blockIdx.x * EPB;

    if (tid < EPB) {
        int dst, src;
        load_idx(ei, flag[0], e0 + tid, dst, src);
        sidx[tid * 2] = dst;
        sidx[tid * 2 + 1] = src;
    }
    __syncthreads();

    // ---- Phase A: 400 distances (one per (edge, atom-pair)), staged in LDS
    for (int item = tid; item < EPB * 25; item += 256) {
        int s = item / 25;
        int p = item - s * 25;
        int i = p / 5;                 // src atom
        int j = p - i * 5;             // dst atom
        int dst = sidx[s * 2], src = sidx[s * 2 + 1];
        const float* S = bb5 + src * 15 + i * 3;
        const float* D = bb5 + dst * 15 + j * 3;
        float dx = S[0] - D[0] + 1e-8f;
        float dy = S[1] - D[1] + 1e-8f;
        float dz = S[2] - D[2] + 1e-8f;
        dist[item] = sqrtf(dx * dx + dy * dy + dz * dz) * 0.8f;
    }

    f32x4* out4 = reinterpret_cast<f32x4*>(out) + (size_t)e0 * 104;

    // ---- Phase C: positional embeddings (threads 0..63)
    // freq[q] = 10^(-q/2) hardcoded (= exp(-q*ln(10000)/8), correctly rounded).
    // angle = (float)(dst-src) * freq; reduce in double to revolutions,
    // then raw v_sin/v_cos (hardware takes revolutions).
    if (tid < EPB * 4) {
        int s = tid >> 2;
        int g = tid & 3;               // 0,1 = cos(f0-3, f4-7); 2,3 = sin
        int dst = sidx[s * 2], src = sidx[s * 2 + 1];
        float d = (float)(dst - src);
        bool hi = (g & 1);             // frequency block: f = hi*4 + k
        bool issin = (g >= 2);
        float fr0 = hi ? 0.01f                    : 1.0f;
        float fr1 = hi ? 0.0031622776601683794f   : 0.31622776601683794f;
        float fr2 = hi ? 0.001f                   : 0.1f;
        float fr3 = hi ? 0.00031622776601683794f  : 0.031622776601683794f;
        float v[4];
        float frs[4] = {fr0, fr1, fr2, fr3};
#pragma unroll
        for (int k = 0; k < 4; ++k) {
            float angle = d * frs[k];                       // f32, matches ref
            double t = (double)angle * 0.15915494309189535; // 1/(2*pi)
            double r = t - rint(t);                         // |r| <= 0.5 revolutions
            float rf = (float)r;
            float val;
            if (issin) {
                asm("v_sin_f32 %0, %1" : "=v"(val) : "v"(rf));
            } else {
                asm("v_cos_f32 %0, %1" : "=v"(val) : "v"(rf));
            }
            v[k] = val;
        }
        f32x4 r4;
        r4.x = v[0]; r4.y = v[1]; r4.z = v[2]; r4.w = v[3];
        out4[s * 104 + 100 + g] = r4;
    }
    __syncthreads();

    // ---- Phase B: RBF chunks, one float4 per thread, fully coalesced
    for (int item = tid; item < EPB * 100; item += 256) {
        int s = item / 100;
        int c = item - s * 100;        // chunk within edge's RBF region
        int p = c >> 2;                // pair index
        int g = c & 3;                 // 4-center group
        float a = dist[s * 25 + p];    // broadcast read (4 lanes share)
        int k0 = g * 4;
        f32x4 r;
        float u;
        u = a - (float)(k0 + 0) * (16.0f / 15.0f); r.x = __expf(-(u * u));
        u = a - (float)(k0 + 1) * (16.0f / 15.0f); r.y = __expf(-(u * u));
        u = a - (float)(k0 + 2) * (16.0f / 15.0f); r.z = __expf(-(u * u));
        u = a - (float)(k0 + 3) * (16.0f / 15.0f); r.w = __expf(-(u * u));
        out4[s * 104 + c] = r;
    }
}

extern "C" void kernel_launch(void* const* d_in, const int* in_sizes, int n_in,
                              void* d_out, int out_size, void* d_ws, size_t ws_size,
                              hipStream_t stream) {
    const float* bb = (const float*)d_in[0];
    const int* ei = (const int*)d_in[1];
    int* flag = (int*)d_ws;
    float* bb5 = (float*)((char*)d_ws + 64);
    float* out = (float*)d_out;

    hipLaunchKernelGGL(prep_kernel, dim3((NN + 255) / 256), dim3(256), 0, stream,
                       bb, ei, flag, bb5);
    hipLaunchKernelGGL(edge_kernel, dim3(EDGE_BLOCKS), dim3(256), 0, stream,
                       ei, bb5, flag, out);
}